// Round 2
// baseline (503.615 us; speedup 1.0000x reference)
//
#include <hip/hip_runtime.h>

typedef short short8 __attribute__((ext_vector_type(8)));
typedef float f32x4 __attribute__((ext_vector_type(4)));
typedef float v2f __attribute__((ext_vector_type(2)));
typedef float v4f __attribute__((ext_vector_type(4)));
typedef unsigned int uint32;

namespace {
constexpr int S_LEN = 512, BATCH = 1024, TAG = 64;
constexpr int START_IDX = 0, END_IDX = 1;
constexpr int LDSS = 72;  // col stride in bf16: +8 pad -> 16B aligned b128 reads, 2-way banks (free)
constexpr int PD = 4;     // feat/mask prefetch depth == renorm cadence

// pack two fp32 -> two bf16 (truncation; bias ~0.2% ok vs threshold 47)
__device__ __forceinline__ uint32 pack_bf16_trunc(float lo, float hi) {
  return __builtin_amdgcn_perm(__float_as_uint(hi), __float_as_uint(lo), 0x07060302u);
}
}  // namespace

// ---------------- kernel 1: per-(batch,chunk) transfer matrix via MFMA ----------------
// M <- diag(exp(feat_s)) * (E * M), E = exp(trans) const in A-frags.
// LDS holds M col-major (M^T), bf16, stride LDSS.
__global__ __launch_bounds__(64) void crf_chunk_kernel(
    const float* __restrict__ feats, const float* __restrict__ mask,
    const float* __restrict__ trans, uint32* __restrict__ wsM,
    float* __restrict__ wsL, int K, int L, int kshift) {
  const int bc = blockIdx.x;
  const int b = bc >> kshift;
  const int c = bc & (K - 1);
  const int lane = threadIdx.x;
  const int c0 = lane & 15, quad = lane >> 4;

  __shared__ __align__(16) unsigned short Mlds[TAG * LDSS];
  __shared__ __align__(16) float f_lds[TAG];

  // ---- init M = I ----
  {
    uint32* p = (uint32*)Mlds;
#pragma unroll
    for (int t = 0; t < (TAG * LDSS / 2) / 64; ++t) p[lane + 64 * t] = 0u;
    __builtin_amdgcn_wave_barrier();
    Mlds[lane * LDSS + lane] = 0x3F80;  // addr = col*LDSS + row, col==row==lane
    __builtin_amdgcn_wave_barrier();
  }

  // ---- E fragments (A-operand): A[m=lane&15][k=quad*8+j] per (mt,kb) tile ----
  short8 Efrag[4][2];
#pragma unroll
  for (int mt = 0; mt < 4; ++mt)
#pragma unroll
    for (int kb = 0; kb < 2; ++kb) {
      const float* src = trans + (mt * 16 + c0) * TAG + kb * 32 + quad * 8;
      v4f t0, t1;
      __builtin_memcpy(&t0, src, 16);
      __builtin_memcpy(&t1, src + 4, 16);
      uint32 uu[4];
      uu[0] = pack_bf16_trunc(__expf(t0.x), __expf(t0.y));
      uu[1] = pack_bf16_trunc(__expf(t0.z), __expf(t0.w));
      uu[2] = pack_bf16_trunc(__expf(t1.x), __expf(t1.y));
      uu[3] = pack_bf16_trunc(__expf(t1.z), __expf(t1.w));
      __builtin_memcpy(&Efrag[mt][kb], uu, 16);
    }

  const size_t FSTRIDE = (size_t)BATCH * TAG;
  const float* fptr = feats + (size_t)(c * L) * FSTRIDE + (size_t)b * TAG + lane;
  const float* mptr = mask + (size_t)(c * L) * BATCH + b;

  float fbuf[PD], mbuf[PD];
#pragma unroll
  for (int d = 0; d < PD; ++d) {
    fbuf[d] = fptr[(size_t)d * FSTRIDE];
    mbuf[d] = mptr[(size_t)d * BATCH];
  }

  float acc_log = 0.0f;

  for (int sb = 0; sb < L; sb += PD) {
#pragma unroll
    for (int d = 0; d < PD; ++d) {
      const float fcur = fbuf[d];
      const float mcur = mbuf[d];
      if (mcur == 0.0f) goto fin;  // mask monotone: rest of chunk is identity
      int sp = sb + d + PD;
      sp = (sp < L) ? sp : (L - 1);
      fbuf[d] = fptr[(size_t)sp * FSTRIDE];
      mbuf[d] = mptr[(size_t)sp * BATCH];

      f_lds[lane] = __expf(fcur);  // f_row, |feat|<~6 so no anchor needed
      __builtin_amdgcn_wave_barrier();

      // B-frags: B[k=quad*8+j][n=lane&15] per (kb,nt); col-major M^T -> contiguous 16B
      short8 Bf[2][4];
#pragma unroll
      for (int kb = 0; kb < 2; ++kb)
#pragma unroll
        for (int nt = 0; nt < 4; ++nt)
          __builtin_memcpy(&Bf[kb][nt],
                           (const char*)Mlds + (nt * 16 + c0) * (LDSS * 2) + kb * 64 + quad * 16,
                           16);

      // G = E*M : 4x4 output tiles, K=64 in 2 MFMAs
      f32x4 g[4][4];
#pragma unroll
      for (int mt = 0; mt < 4; ++mt)
#pragma unroll
        for (int nt = 0; nt < 4; ++nt) {
          f32x4 z = {0.f, 0.f, 0.f, 0.f};
          z = __builtin_amdgcn_mfma_f32_16x16x32_bf16(Efrag[mt][0], Bf[0][nt], z, 0, 0, 0);
          g[mt][nt] = __builtin_amdgcn_mfma_f32_16x16x32_bf16(Efrag[mt][1], Bf[1][nt], z, 0, 0, 0);
        }

      // row scales: C/D rows = mt*16 + quad*4 + reg
      v4f fr[4];
#pragma unroll
      for (int mt = 0; mt < 4; ++mt)
        __builtin_memcpy(&fr[mt], f_lds + mt * 16 + quad * 4, 16);

#pragma unroll
      for (int mt = 0; mt < 4; ++mt)
#pragma unroll
        for (int nt = 0; nt < 4; ++nt) {
          g[mt][nt].x *= fr[mt].x;
          g[mt][nt].y *= fr[mt].y;
          g[mt][nt].z *= fr[mt].z;
          g[mt][nt].w *= fr[mt].w;
        }

      if (d == PD - 1) {  // renorm every 4 steps: growth <= 2^15/step -> <=2^60, safe
        f32x4 sv = {0.f, 0.f, 0.f, 0.f};
#pragma unroll
        for (int mt = 0; mt < 4; ++mt)
#pragma unroll
          for (int nt = 0; nt < 4; ++nt) {
            sv.x += g[mt][nt].x;
            sv.y += g[mt][nt].y;
            sv.z += g[mt][nt].z;
            sv.w += g[mt][nt].w;
          }
        float r = (sv.x + sv.y) + (sv.z + sv.w);
#pragma unroll
        for (int off = 32; off >= 1; off >>= 1) r += __shfl_xor(r, off, 64);
        acc_log += __logf(r);
        const float inv = 1.0f / r;
#pragma unroll
        for (int mt = 0; mt < 4; ++mt)
#pragma unroll
          for (int nt = 0; nt < 4; ++nt) {
            g[mt][nt].x *= inv;
            g[mt][nt].y *= inv;
            g[mt][nt].z *= inv;
            g[mt][nt].w *= inv;
          }
      }

      __builtin_amdgcn_wave_barrier();  // pin: B-frag reads before M overwrite
#pragma unroll
      for (int mt = 0; mt < 4; ++mt)
#pragma unroll
        for (int nt = 0; nt < 4; ++nt) {
          uint32 uu[2];
          uu[0] = pack_bf16_trunc(g[mt][nt].x, g[mt][nt].y);
          uu[1] = pack_bf16_trunc(g[mt][nt].z, g[mt][nt].w);
          __builtin_memcpy((char*)Mlds + (nt * 16 + c0) * (LDSS * 2) + (mt * 16 + quad * 4) * 2,
                           uu, 8);
        }
      __builtin_amdgcn_wave_barrier();
    }
  }
fin:
  __builtin_amdgcn_wave_barrier();
  // transpose col-major LDS -> row-major global; lane j writes row j (128 B contiguous)
  {
    uint32 rowpk[32];
#pragma unroll
    for (int i2 = 0; i2 < 32; ++i2) {
      const unsigned short e0 = Mlds[(2 * i2) * LDSS + lane];
      const unsigned short e1 = Mlds[(2 * i2 + 1) * LDSS + lane];
      rowpk[i2] = (uint32)e0 | ((uint32)e1 << 16);
    }
    uint32* dst = wsM + (size_t)bc * 2048 + lane * 32;
#pragma unroll
    for (int t = 0; t < 8; ++t) {
      uint32 q[4] = {rowpk[4 * t], rowpk[4 * t + 1], rowpk[4 * t + 2], rowpk[4 * t + 3]};
      __builtin_memcpy(dst + 4 * t, q, 16);
    }
    if (lane == 0) wsL[bc] = acc_log;
  }
}

// ---------------- kernel 2: stitch K chunk matrices per batch ----------------
__global__ __launch_bounds__(64) void crf_stitch_kernel(
    const uint32* __restrict__ wsM, const float* __restrict__ wsL,
    const float* __restrict__ trans, float* __restrict__ out, int K) {
  const int b = blockIdx.x;
  const int lane = threadIdx.x;
  __shared__ __align__(16) float a_lds[TAG];

  typedef uint32 u32x4 __attribute__((ext_vector_type(4)));
  u32x4 cur[8], nxt[8];
  {
    const uint32* p0 = wsM + ((size_t)b * K) * 2048 + lane * 32;
#pragma unroll
    for (int t = 0; t < 8; ++t) __builtin_memcpy(&cur[t], p0 + 4 * t, 16);
  }

  float a = (lane == START_IDX) ? 1.0f : 0.0f;
  float tot = 0.0f;

  for (int c = 0; c < K; ++c) {
    if (c + 1 < K) {
      const uint32* pn = wsM + ((size_t)b * K + c + 1) * 2048 + lane * 32;
#pragma unroll
      for (int t = 0; t < 8; ++t) __builtin_memcpy(&nxt[t], pn + 4 * t, 16);
    }
    a_lds[lane] = a;
    __builtin_amdgcn_wave_barrier();
    v2f acc[4] = {{0.f, 0.f}, {0.f, 0.f}, {0.f, 0.f}, {0.f, 0.f}};
#pragma unroll
    for (int t = 0; t < 8; ++t) {
#pragma unroll
      for (int e = 0; e < 4; ++e) {
        const uint32 u = cur[t][e];
        v2f m = {__uint_as_float(u << 16), __uint_as_float(u & 0xFFFF0000u)};
        v2f av;
        __builtin_memcpy(&av, a_lds + 8 * t + 2 * e, 8);  // broadcast read
        acc[e] += m * av;                                  // v_pk_fma_f32
      }
    }
    const v2f accT = (acc[0] + acc[1]) + (acc[2] + acc[3]);
    const float s = accT.x + accT.y;  // new a_lane (>=0)
    __builtin_amdgcn_wave_barrier();  // reads done before next a_lds write
    float r = s;
#pragma unroll
    for (int off = 32; off >= 1; off >>= 1) r += __shfl_xor(r, off, 64);
    tot += __logf(r);
    a = s / r;
    if (c + 1 < K) {
#pragma unroll
      for (int t = 0; t < 8; ++t) cur[t] = nxt[t];
    }
  }

  const float eend = __expf(trans[END_IDX * TAG + lane]);
  float v = a * eend;
#pragma unroll
  for (int off = 32; off >= 1; off >>= 1) v += __shfl_xor(v, off, 64);
  float logs = tot;
  for (int c = 0; c < K; ++c) logs += wsL[b * K + c];
  if (lane == 0) out[b] = logs + __logf(v);
}

// ---------------- fallback (round-1 sequential kernel) if ws too small ----------------
__global__ __launch_bounds__(64) void crf_fwd_fallback(
    const float* __restrict__ feats, const float* __restrict__ mask,
    const float* __restrict__ trans, float* __restrict__ out) {
  const int b = blockIdx.x;
  const int lane = threadIdx.x;
  __shared__ float p_lds[TAG];
  v2f E[TAG / 2];
  {
    const float* row = trans + lane * TAG;
#pragma unroll
    for (int k = 0; k < TAG / 4; ++k) {
      v4f tv;
      __builtin_memcpy(&tv, row + 4 * k, sizeof(v4f));
      E[2 * k] = (v2f){__expf(tv.x), __expf(tv.y)};
      E[2 * k + 1] = (v2f){__expf(tv.z), __expf(tv.w)};
    }
  }
  float alpha = (lane == START_IDX) ? 0.0f : -10000.0f;
  float hatM = 0.0f;
  const float* fptr = feats + (size_t)b * TAG + lane;
  const float* mptr = mask + b;
  float fbuf[8], mbuf[8];
#pragma unroll
  for (int d = 0; d < 8; ++d) {
    fbuf[d] = fptr[(size_t)d * (BATCH * TAG)];
    mbuf[d] = mptr[(size_t)d * BATCH];
  }
  for (int sb = 0; sb < S_LEN; sb += 8) {
#pragma unroll
    for (int d = 0; d < 8; ++d) {
      const float fcur = fbuf[d], mcur = mbuf[d];
      if (mcur == 0.0f) goto fin;
      int sp = sb + d + 8;
      sp = (sp < S_LEN) ? sp : (S_LEN - 1);
      fbuf[d] = fptr[(size_t)sp * (BATCH * TAG)];
      mbuf[d] = mptr[(size_t)sp * BATCH];
      const float p = __expf(alpha - hatM);
      p_lds[lane] = p;
      __builtin_amdgcn_wave_barrier();
      v2f a0 = {0.f, 0.f}, a1 = {0.f, 0.f}, a2 = {0.f, 0.f}, a3 = {0.f, 0.f};
#pragma unroll
      for (int k = 0; k < TAG / 8; ++k) {
        v2f p0, p1, p2, p3;
        __builtin_memcpy(&p0, p_lds + 8 * k + 0, 8);
        __builtin_memcpy(&p1, p_lds + 8 * k + 2, 8);
        __builtin_memcpy(&p2, p_lds + 8 * k + 4, 8);
        __builtin_memcpy(&p3, p_lds + 8 * k + 6, 8);
        a0 += p0 * E[4 * k + 0];
        a1 += p1 * E[4 * k + 1];
        a2 += p2 * E[4 * k + 2];
        a3 += p3 * E[4 * k + 3];
      }
      const v2f aT = (a0 + a1) + (a2 + a3);
      alpha = fcur + hatM + __logf(aT.x + aT.y);
      hatM = __uint_as_float(__builtin_amdgcn_readlane(__float_as_uint(alpha), 2));
      __builtin_amdgcn_wave_barrier();
    }
  }
fin : {
  const float aend = alpha + trans[END_IDX * TAG + lane];
  float mx = aend;
#pragma unroll
  for (int off = 32; off >= 1; off >>= 1) mx = fmaxf(mx, __shfl_xor(mx, off, 64));
  float e = __expf(aend - mx);
#pragma unroll
  for (int off = 32; off >= 1; off >>= 1) e += __shfl_xor(e, off, 64);
  if (lane == 0) out[b] = mx + __logf(e);
}
}

extern "C" void kernel_launch(void* const* d_in, const int* in_sizes, int n_in,
                              void* d_out, int out_size, void* d_ws, size_t ws_size,
                              hipStream_t stream) {
  const float* feats = (const float*)d_in[0];
  const float* mask = (const float*)d_in[1];
  const float* trans = (const float*)d_in[2];
  float* out = (float*)d_out;

  int K = 0, kshift = 0;
  {
    int ks = 3;
    for (int k = 8; k >= 2; k >>= 1, --ks) {
      size_t need = (size_t)BATCH * k * (TAG * TAG * 2 + 4) + 256;
      if (ws_size >= need) {
        K = k;
        kshift = ks;
        break;
      }
    }
  }
  if (K == 0) {
    crf_fwd_fallback<<<dim3(BATCH), dim3(64), 0, stream>>>(feats, mask, trans, out);
    return;
  }
  uint32* wsM = (uint32*)d_ws;
  float* wsL = (float*)((char*)d_ws + (size_t)BATCH * K * TAG * TAG * 2);
  crf_chunk_kernel<<<dim3(BATCH * K), dim3(64), 0, stream>>>(feats, mask, trans, wsM, wsL, K,
                                                             S_LEN / K, kshift);
  crf_stitch_kernel<<<dim3(BATCH), dim3(64), 0, stream>>>(wsM, wsL, trans, out, K);
}